// Round 5
// baseline (303.178 us; speedup 1.0000x reference)
//
#include <hip/hip_runtime.h>
#include <hip/hip_bf16.h>

#define BQ    4
#define QL    512
#define KVL   2048
#define PASTN 1536
#define NKV   8
#define DH    128
#define BPS   128

typedef __bf16 bf16x8 __attribute__((ext_vector_type(8)));
typedef float  f32x4  __attribute__((ext_vector_type(4)));
typedef float  f32x16 __attribute__((ext_vector_type(16)));

#if __has_builtin(__builtin_amdgcn_exp2f)
#define EXP2F(x) __builtin_amdgcn_exp2f(x)
#else
#define EXP2F(x) exp2f(x)
#endif

// round-to-nearest-even f32 -> bf16 (inputs finite; no NaN handling needed)
__device__ __forceinline__ unsigned short f32_to_bf16(float f) {
    unsigned u = __builtin_bit_cast(unsigned, f);
    u += 0x7fffu + ((u >> 16) & 1u);
    return (unsigned short)(u >> 16);
}

__device__ __forceinline__ unsigned pk_bf16(float a, float b) {
    return (unsigned)f32_to_bf16(a) | ((unsigned)f32_to_bf16(b) << 16);
}

// truncating bf16x2 pack: one v_perm_b32. Bias cancels because l is summed
// from the SAME packed values.
__device__ __forceinline__ unsigned pk_trunc(float lo, float hi) {
    return __builtin_amdgcn_perm(__builtin_bit_cast(unsigned, hi),
                                 __builtin_bit_cast(unsigned, lo), 0x07060302u);
}

// direct global->LDS async copy, 16B per lane; LDS dest is wave-uniform base,
// HW adds lane*16. Global src is per-lane (carries the inverse swizzle).
__device__ __forceinline__ void load_lds16(const unsigned short* g, unsigned short* l) {
    __builtin_amdgcn_global_load_lds(
        (const __attribute__((address_space(1))) void*)g,
        (__attribute__((address_space(3))) void*)l, 16, 0, 0);
}

// v_permlane32_swap_b32 vdst, vsrc: new vdst = [vdst 0-31 | vsrc 0-31],
//                                   new vsrc = [vdst 32-63 | vsrc 32-63].
// x and y MUST be distinct values (regalloc coalesces equal SSA values into
// one VGPR -> in-place half-swap; broke round 2's epilogue).
__device__ __forceinline__ void swap32(unsigned &x, unsigned &y) {
    asm("v_permlane32_swap_b32 %0, %1" : "+v"(x), "+v"(y));
}

// add both bf16 halves of packed p into L (bf16 -> f32 is a shift)
__device__ __forceinline__ void lacc_add(float &L, unsigned p) {
    L += __builtin_bit_cast(float, p << 16);
    L += __builtin_bit_cast(float, p & 0xffff0000u);
}

// ---------------- merged pre-pass: gather K -> bf16 K[b][h][kv][d]  (blocks 0..8191)
//                  and gather V + transpose -> bf16 VT[b][h][d][kv]  (blocks 8192..9215)
#define VLS 130   // Vl row stride in shorts: 4*VLS mod 64 = 8 -> transpose reads
                  // spread over 4 bank-groups (2-way, free) vs 132's 4-way.
                  // 130 is not 0 mod 4 -> rows only 4B-aligned: write as 2x u32.
__global__ __launch_bounds__(256) void gather_kv_kernel(
    const float* __restrict__ key, const float* __restrict__ key_cache,
    const float* __restrict__ value, const float* __restrict__ value_cache,
    const int* __restrict__ bt, unsigned short* __restrict__ Kb,
    unsigned short* __restrict__ VTb)
{
  __shared__ unsigned short Vl[64 * VLS];
  const int bid = blockIdx.x;
  if (bid < 8192) {
    // ---- K gather
    const int gidx = bid * 256 + threadIdx.x;
    const int d  = (gidx & 31) * 4;
    const int p  = (gidx >> 5) & (KVL - 1);
    const int bh = gidx >> 16;
    const int hh = bh & 7;
    const int bb = bh >> 3;
    const float* src;
    if (p < PASTN) {
      const int blk = bt[bb * BPS + (p >> 4)];
      src = key_cache + (size_t)((blk * 16 + (p & 15)) * 8 + hh) * DH + d;
    } else {
      src = key + (size_t)((bb * QL + (p - PASTN)) * 8 + hh) * DH + d;
    }
    const float4 v = *(const float4*)src;
    uint2 o;
    o.x = pk_bf16(v.x, v.y);
    o.y = pk_bf16(v.z, v.w);
    *(uint2*)(Kb + ((size_t)bh * KVL + p) * DH + d) = o;
  } else {
    // ---- V gather + transpose
    const int vbid = bid - 8192;
    const int t   = vbid & 31;
    const int hh  = (vbid >> 5) & 7;
    const int bb  = vbid >> 8;
    const int tid = threadIdx.x;
    const int dl  = (tid & 31) * 4;
    const int p0  = tid >> 5;
#pragma unroll
    for (int it = 0; it < 8; ++it) {
      const int pl = p0 + it * 8;
      const int gp = t * 64 + pl;
      const float* src;
      if (gp < PASTN) {
        const int blk = bt[bb * BPS + (gp >> 4)];
        src = value_cache + (size_t)((blk * 16 + (gp & 15)) * 8 + hh) * DH + dl;
      } else {
        src = value + (size_t)((bb * QL + (gp - PASTN)) * 8 + hh) * DH + dl;
      }
      const float4 v = *(const float4*)src;
      unsigned short* dst = &Vl[pl * VLS + dl];
      *(unsigned*)(dst)     = pk_bf16(v.x, v.y);
      *(unsigned*)(dst + 2) = pk_bf16(v.z, v.w);
    }
    __syncthreads();
#pragma unroll
    for (int it = 0; it < 4; ++it) {
      const int slot = it * 256 + tid;
      const int d    = slot >> 3;
      const int kv0  = (slot & 7) * 8;
      unsigned rr[4];
#pragma unroll
      for (int i = 0; i < 4; ++i) {
        const unsigned lo = Vl[(kv0 + 2 * i) * VLS + d];
        const unsigned hi = Vl[(kv0 + 2 * i + 1) * VLS + d];
        rr[i] = lo | (hi << 16);
      }
      *(uint4*)(VTb + ((size_t)(bb * 8 + hh) * DH + d) * KVL + t * 64 + kv0) =
          make_uint4(rr[0], rr[1], rr[2], rr[3]);
    }
  }
}

// ---------------- fused causal GQA flash attention (32x32x16 MFMA, KV-split)
// grid 512 = b(4)*h(8)*qb(16); 512 threads = 8 waves = 2 KV-groups x 4 GQA heads.
// Work-parallelism was the round-3/4 wall (2048 wave-tasks = 2 waves/SIMD,
// latency-bound, no pipe >45%). The no-max exp2 softmax makes KV-split partials
// ADDITIVE (O = O0+O1, l = l0+l1, no rescale), so group g handles 32-kv tiles
// m = g, g+2, g+4, ... with its own double-buffered 16KB K + 16KB VT region.
// Same total LDS traffic / MFMA count / barrier count as round 3, but
// 16 waves/CU = 4 waves/SIMD. End: group 1 dumps partial O (reuses the 64KB
// staging LDS exactly) + l; group 0 combines, divides, stores.
// Bonus: 32-kv tiles put the causal boundary exactly on the diagonal
// (in-tile offset is always 0) -> no fully-masked half-tiles.
__global__ __launch_bounds__(512, 4) void attn_kernel(
    const float* __restrict__ query,
    const unsigned short* __restrict__ Kb,
    const unsigned short* __restrict__ VTb,
    float* __restrict__ out)
{
  // [0..16383]        : K staging, 4 regions (grp,buf) of 4096 shorts (32x128)
  // [16384..32767]    : VT staging, 4 regions (grp,buf) of 4096 shorts (128x32)
  // combine phase     : shorts [0..32767] reused as 16384-float partial-O buffer
  // [32768..33279]    : 256-float l buffer
  __shared__ unsigned short SM[33280];

  const int tid  = threadIdx.x;
  const int w    = tid >> 6;
  const int grp  = w >> 2;       // KV half
  const int wh   = w & 3;        // GQA head within group
  const int lane = tid & 63;
  const int cq   = lane & 31;    // q column (and A-row for K/V frags)
  const int hi   = lane >> 5;
  const int xk   = cq & 7;       // XOR-swizzle key, K rows (256B = 16 units)
  const int xk3  = cq & 3;       // XOR-swizzle key, VT rows (64B = 4 units)

  const int gid = blockIdx.x;
  const int qb  = gid >> 5;          // 0..15
  const int bh  = gid & 31;
  const int b   = bh >> 3;
  const int h   = bh & 7;
  const int q0  = qb * 32;
  // 32-kv tiles needed: ceil((PASTN + q0 + 32)/32) = 49 + qb (exact diagonal fit)
  const int M     = (PASTN >> 5) + 1 + qb;
  const int ITmax = (M + 1) >> 1;
  // group owning the diagonal tile M-1 applies the (rr > cq) mask there
  const int mask_it = (((M - 1) & 1) == grp) ? ((M - 1 - grp) >> 1) : -1;
  const int hq  = h * 4 + wh;

  // per-lane swizzled GLOBAL source addresses for direct-to-LDS staging.
  // K tile: 32 rows x 256B; wave stages rows 8wh..8wh+7 (2 x 1KB issues of 4 rows)
  const int kx = lane >> 4;      // row within issue quad
  const int ku = lane & 15;      // 16B unit within row
  const unsigned short* kgp[2];
#pragma unroll
  for (int i = 0; i < 2; ++i) {
    const int rl = 8 * wh + 4 * i + kx;                 // tile-local row
    kgp[i] = Kb + ((size_t)bh * KVL + grp * 32 + rl) * DH + (ku ^ (rl & 7)) * 8;
  }
  // VT tile: 128 rows(d) x 64B; wave stages rows 32wh..32wh+31 (2 x 1KB issues of 16 rows)
  const int vr4 = lane >> 2;     // row within issue 16-group
  const int vu  = lane & 3;      // 16B unit within row
  const unsigned short* vgp[2];
#pragma unroll
  for (int i = 0; i < 2; ++i) {
    const int rl = 32 * wh + 16 * i + vr4;              // d row
    vgp[i] = VTb + ((size_t)bh * DH + rl) * KVL + grp * 32 + (vu ^ (vr4 & 3)) * 8;
  }

  auto issue_tile = [&](int buf) {
    unsigned short* kb = &SM[(grp * 2 + buf) * 4096 + wh * 1024];
    load_lds16(kgp[0], kb);
    load_lds16(kgp[1], kb + 512);
    unsigned short* vb = kb + 16384;
    load_lds16(vgp[0], vb);
    load_lds16(vgp[1], vb + 512);
    kgp[0] += 64 * DH; kgp[1] += 64 * DH;   // next group-tile: +2 tiles = +64 kv rows
    vgp[0] += 64;      vgp[1] += 64;        // +64 kv cols (shorts)
  };

  issue_tile(0);   // start DMA before Q reads

  // fold 1/sqrt(128) * log2(e) into Q (softmax done in exp2 domain)
  const float qscale = 0.08838834764831845f * 1.4426950408889634f;

  // Q B-fragments: lane holds Q[q0+cq][16*ks + 8*hi + j], j=0..7
  bf16x8 qf[8];
  {
    const float* qp = query + (size_t)(b * QL + q0 + cq) * 4096 + hq * DH + 8 * hi;
#pragma unroll
    for (int ks = 0; ks < 8; ++ks) {
      float4 x = *(const float4*)(qp + 16 * ks);
      float4 y = *(const float4*)(qp + 16 * ks + 4);
      uint4 u;
      u.x = pk_bf16(x.x * qscale, x.y * qscale);
      u.y = pk_bf16(x.z * qscale, x.w * qscale);
      u.z = pk_bf16(y.x * qscale, y.y * qscale);
      u.w = pk_bf16(y.z * qscale, y.w * qscale);
      qf[ks] = __builtin_bit_cast(bf16x8, u);
    }
  }

  f32x16 Oacc[4];
#pragma unroll
  for (int dt = 0; dt < 4; ++dt)
#pragma unroll
    for (int i = 0; i < 16; ++i) Oacc[dt][i] = 0.f;
  float Ls = 0.f;

  for (int it = 0; it < ITmax; ++it) {
    const int buf = it & 1;
    __syncthreads();                               // drains vmcnt: tile staged
    if (2 * (it + 1) + grp < M) issue_tile(buf ^ 1);
    if (2 * it + grp < M) {
      const unsigned short* Kr = &SM[(grp * 2 + buf) * 4096];
      const unsigned short* Vr = Kr + 16384;

      // ---- S^T[kv 32][q 32] = K * Q^T
      f32x16 S;
#pragma unroll
      for (int i = 0; i < 16; ++i) S[i] = 0.f;
#pragma unroll
      for (int ks = 0; ks < 8; ++ks) {
        const bf16x8 af = __builtin_bit_cast(bf16x8,
            *(const uint4*)&Kr[cq * 128 + 8 * ((2 * ks + hi) ^ xk)]);
        S = __builtin_amdgcn_mfma_f32_32x32x16_bf16(af, qf[ks], S, 0, 0, 0);
      }

      // ---- causal mask on the diagonal tile (in-tile offset is always 0)
      if (it == mask_it) {
#pragma unroll
        for (int reg = 0; reg < 16; ++reg) {
          const int rr = (reg & 3) + 8 * (reg >> 2) + 4 * hi;
          if (rr > cq) S[reg] = -1e30f;
        }
      }

      // ---- softmax + in-register P assembly + PV, per 16-kv step
#pragma unroll
      for (int s = 0; s < 2; ++s) {
        unsigned p01 = pk_trunc(EXP2F(S[8 * s + 0]), EXP2F(S[8 * s + 1]));
        unsigned p23 = pk_trunc(EXP2F(S[8 * s + 2]), EXP2F(S[8 * s + 3]));
        unsigned q01 = pk_trunc(EXP2F(S[8 * s + 4]), EXP2F(S[8 * s + 5]));
        unsigned q23 = pk_trunc(EXP2F(S[8 * s + 6]), EXP2F(S[8 * s + 7]));
        lacc_add(Ls, p01); lacc_add(Ls, p23);
        lacc_add(Ls, q01); lacc_add(Ls, q23);
        swap32(p01, q01);
        swap32(p23, q23);
        uint4 u; u.x = p01; u.y = p23; u.z = q01; u.w = q23;
        const bf16x8 pf = __builtin_bit_cast(bf16x8, u);
#pragma unroll
        for (int dt = 0; dt < 4; ++dt) {
          const bf16x8 vf = __builtin_bit_cast(bf16x8,
              *(const uint4*)&Vr[(32 * dt + cq) * 32 + 8 * ((2 * s + hi) ^ xk3)]);
          Oacc[dt] = __builtin_amdgcn_mfma_f32_32x32x16_bf16(vf, pf, Oacc[dt], 0, 0, 0);
        }
      }
    }
  }

  // ---- combine the two KV halves (partials are additive: no max-rescale),
  //      then cross-half l via shfl_xor, divide, store.
  __syncthreads();
  float* Ob = (float*)&SM[0];          // 16384 floats (reuses staging LDS)
  float* Lb = (float*)&SM[32768];      // 256 floats
  const int l15 = lane & 15;
  if (grp == 1) {
    Lb[wh * 64 + lane] = Ls;
    float* myO = Ob + wh * 4096 + lane * 64;
#pragma unroll
    for (int dt = 0; dt < 4; ++dt)
#pragma unroll
      for (int rq = 0; rq < 4; ++rq) {
        f32x4 c;
        c[0] = Oacc[dt][4 * rq + 0]; c[1] = Oacc[dt][4 * rq + 1];
        c[2] = Oacc[dt][4 * rq + 2]; c[3] = Oacc[dt][4 * rq + 3];
        *(f32x4*)(myO + ((dt * 4 + rq) ^ l15) * 4) = c;   // XOR chunk-swizzle: uniform banks
      }
  }
  __syncthreads();
  if (grp == 0) {
    const float Lsum  = Ls + Lb[wh * 64 + lane];
    const float other = __shfl_xor(Lsum, 32, 64);
    const float inv   = 1.0f / (Lsum + other);
    const float* myO = Ob + wh * 4096 + lane * 64;
    float* op = out + (size_t)(b * QL + q0 + cq) * 4096 + hq * DH + 4 * hi;
#pragma unroll
    for (int dt = 0; dt < 4; ++dt) {
#pragma unroll
      for (int rq = 0; rq < 4; ++rq) {
        const f32x4 c = *(const f32x4*)(myO + ((dt * 4 + rq) ^ l15) * 4);
        float4 o4;
        o4.x = (Oacc[dt][4 * rq + 0] + c[0]) * inv;
        o4.y = (Oacc[dt][4 * rq + 1] + c[1]) * inv;
        o4.z = (Oacc[dt][4 * rq + 2] + c[2]) * inv;
        o4.w = (Oacc[dt][4 * rq + 3] + c[3]) * inv;
        *(float4*)(op + 32 * dt + 8 * rq) = o4;
      }
    }
  }
}

extern "C" void kernel_launch(void* const* d_in, const int* in_sizes, int n_in,
                              void* d_out, int out_size, void* d_ws, size_t ws_size,
                              hipStream_t stream) {
  const float* query = (const float*)d_in[0];
  const float* key   = (const float*)d_in[1];
  const float* value = (const float*)d_in[2];
  const float* kc    = (const float*)d_in[3];
  const float* vc    = (const float*)d_in[4];
  const int*   bt    = (const int*)d_in[5];
  float* out = (float*)d_out;

  unsigned short* Kb  = (unsigned short*)d_ws;                 // 16.78 MB
  unsigned short* VTb = Kb + (size_t)32 * KVL * DH;            // + 16.78 MB

  gather_kv_kernel<<<9216, 256, 0, stream>>>(key, kc, value, vc, bt, Kb, VTb);
  attn_kernel<<<512, 512, 0, stream>>>(query, Kb, VTb, out);
}

// Round 6
// 228.490 us; speedup vs baseline: 1.3269x; 1.3269x over previous
//
#include <hip/hip_runtime.h>
#include <hip/hip_bf16.h>

#define BQ    4
#define QL    512
#define KVL   2048
#define PASTN 1536
#define NKV   8
#define DH    128
#define BPS   128

typedef __bf16 bf16x8 __attribute__((ext_vector_type(8)));
typedef float  f32x4  __attribute__((ext_vector_type(4)));
typedef float  f32x16 __attribute__((ext_vector_type(16)));

#if __has_builtin(__builtin_amdgcn_exp2f)
#define EXP2F(x) __builtin_amdgcn_exp2f(x)
#else
#define EXP2F(x) exp2f(x)
#endif

// round-to-nearest-even f32 -> bf16 (inputs finite; no NaN handling needed)
__device__ __forceinline__ unsigned short f32_to_bf16(float f) {
    unsigned u = __builtin_bit_cast(unsigned, f);
    u += 0x7fffu + ((u >> 16) & 1u);
    return (unsigned short)(u >> 16);
}

__device__ __forceinline__ unsigned pk_bf16(float a, float b) {
    return (unsigned)f32_to_bf16(a) | ((unsigned)f32_to_bf16(b) << 16);
}

// truncating bf16x2 pack: one v_perm_b32. Bias cancels because l is summed
// from the SAME packed values.
__device__ __forceinline__ unsigned pk_trunc(float lo, float hi) {
    return __builtin_amdgcn_perm(__builtin_bit_cast(unsigned, hi),
                                 __builtin_bit_cast(unsigned, lo), 0x07060302u);
}

// direct global->LDS async copy, 16B per lane; LDS dest is wave-uniform base,
// HW adds lane*16. Global src is per-lane (carries the inverse swizzle).
__device__ __forceinline__ void load_lds16(const unsigned short* g, unsigned short* l) {
    __builtin_amdgcn_global_load_lds(
        (const __attribute__((address_space(1))) void*)g,
        (__attribute__((address_space(3))) void*)l, 16, 0, 0);
}

// v_permlane32_swap_b32 vdst, vsrc: new vdst = [vdst 0-31 | vsrc 0-31],
//                                   new vsrc = [vdst 32-63 | vsrc 32-63].
// x and y MUST be distinct values (regalloc coalesces equal SSA values into
// one VGPR -> in-place half-swap; broke round 2's epilogue).
__device__ __forceinline__ void swap32(unsigned &x, unsigned &y) {
    asm("v_permlane32_swap_b32 %0, %1" : "+v"(x), "+v"(y));
}

// add both bf16 halves of packed p into L (bf16 -> f32 is a shift)
__device__ __forceinline__ void lacc_add(float &L, unsigned p) {
    L += __builtin_bit_cast(float, p << 16);
    L += __builtin_bit_cast(float, p & 0xffff0000u);
}

// ---------------- merged pre-pass: gather K -> bf16 K[b][h][kv][d]  (blocks 0..8191)
//                  and gather V + transpose -> bf16 VT[b][h][d][kv]  (blocks 8192..9215)
#define VLS 130   // Vl row stride in shorts: transpose reads spread over bank
                  // groups (2-way max, free). Rows only 4B-aligned: write 2x u32.
__global__ __launch_bounds__(256) void gather_kv_kernel(
    const float* __restrict__ key, const float* __restrict__ key_cache,
    const float* __restrict__ value, const float* __restrict__ value_cache,
    const int* __restrict__ bt, unsigned short* __restrict__ Kb,
    unsigned short* __restrict__ VTb)
{
  __shared__ unsigned short Vl[64 * VLS];
  const int bid = blockIdx.x;
  if (bid < 8192) {
    // ---- K gather
    const int gidx = bid * 256 + threadIdx.x;
    const int d  = (gidx & 31) * 4;
    const int p  = (gidx >> 5) & (KVL - 1);
    const int bh = gidx >> 16;
    const int hh = bh & 7;
    const int bb = bh >> 3;
    const float* src;
    if (p < PASTN) {
      const int blk = bt[bb * BPS + (p >> 4)];
      src = key_cache + (size_t)((blk * 16 + (p & 15)) * 8 + hh) * DH + d;
    } else {
      src = key + (size_t)((bb * QL + (p - PASTN)) * 8 + hh) * DH + d;
    }
    const float4 v = *(const float4*)src;
    uint2 o;
    o.x = pk_bf16(v.x, v.y);
    o.y = pk_bf16(v.z, v.w);
    *(uint2*)(Kb + ((size_t)bh * KVL + p) * DH + d) = o;
  } else {
    // ---- V gather + transpose
    const int vbid = bid - 8192;
    const int t   = vbid & 31;
    const int hh  = (vbid >> 5) & 7;
    const int bb  = vbid >> 8;
    const int tid = threadIdx.x;
    const int dl  = (tid & 31) * 4;
    const int p0  = tid >> 5;
#pragma unroll
    for (int it = 0; it < 8; ++it) {
      const int pl = p0 + it * 8;
      const int gp = t * 64 + pl;
      const float* src;
      if (gp < PASTN) {
        const int blk = bt[bb * BPS + (gp >> 4)];
        src = value_cache + (size_t)((blk * 16 + (gp & 15)) * 8 + hh) * DH + dl;
      } else {
        src = value + (size_t)((bb * QL + (gp - PASTN)) * 8 + hh) * DH + dl;
      }
      const float4 v = *(const float4*)src;
      unsigned short* dst = &Vl[pl * VLS + dl];
      *(unsigned*)(dst)     = pk_bf16(v.x, v.y);
      *(unsigned*)(dst + 2) = pk_bf16(v.z, v.w);
    }
    __syncthreads();
#pragma unroll
    for (int it = 0; it < 4; ++it) {
      const int slot = it * 256 + tid;
      const int d    = slot >> 3;
      const int kv0  = (slot & 7) * 8;
      unsigned rr[4];
#pragma unroll
      for (int i = 0; i < 4; ++i) {
        const unsigned lo = Vl[(kv0 + 2 * i) * VLS + d];
        const unsigned hi = Vl[(kv0 + 2 * i + 1) * VLS + d];
        rr[i] = lo | (hi << 16);
      }
      *(uint4*)(VTb + ((size_t)(bb * 8 + hh) * DH + d) * KVL + t * 64 + kv0) =
          make_uint4(rr[0], rr[1], rr[2], rr[3]);
    }
  }
}

// ---------------- fused causal GQA flash attention (32x32x16 MFMA)
// grid 512 = b(4)*h(8)*qb(16); 256 threads = 4 waves = 4 GQA heads, each wave
// computes the FULL 64-kv x 32-q tile with mfma_f32_32x32x16_bf16 (round-3
// structure: best measured config, ~86us; rounds 4/5 regressions reverted).
//
// Round-6 change: CONFLICT-FREE LDS swizzle. Round 3's key (row&7) left every
// K/V fragment read 4-way bank-conflicted: row strides 256B/128B are = 0 mod
// 128B, so lanes cq, cq+8, cq+16, cq+24 hit the same bank (key repeats every
// 8 rows). New key folds in the next two row bits:
//     key(row) = (row&7) ^ ((row>>3)&3)
// Per read instruction the 64 lanes' 16B-unit bank-group residues
// (u ^ (cq&7) ^ ((cq>>3)&3)) mod 8 cover each group exactly 8x = the minimum
// -> conflict-free. Same key serves K rows cq / cq+32 and V rows 32*dt+cq
// (the +32 / +4*dt vanish under &3). Staging carries the same involution on
// the per-lane GLOBAL source; LDS dest stays linear (global_load_lds rule).
__global__ __launch_bounds__(256, 2) void attn_kernel(
    const float* __restrict__ query,
    const unsigned short* __restrict__ Kb,
    const unsigned short* __restrict__ VTb,
    float* __restrict__ out)
{
  __shared__ unsigned short Klds[2][64 * 128];    // swizzled linear [kv][d], 32 KB
  __shared__ unsigned short Vtlds[2][128 * 64];   // swizzled linear [d][kv], 32 KB

  const int tid  = threadIdx.x;
  const int w    = tid >> 6;     // GQA head within group
  const int lane = tid & 63;
  const int cq   = lane & 31;    // q column (and A-row for K/V frags)
  const int hi   = lane >> 5;
  const int xkey = (cq & 7) ^ ((cq >> 3) & 3);   // conflict-free read key

  const int gid = blockIdx.x;
  const int qb  = gid >> 5;          // 0..15
  const int bh  = gid & 31;
  const int b   = bh >> 3;
  const int h   = bh & 7;
  const int q0  = qb * 32;
  const int n_tiles = ((PASTN + q0 + 31) >> 6) + 1;     // last needed kv tile, incl.
  const int lim = PASTN + q0 - 64 * (n_tiles - 1);      // in-tile causal offset (0 or 32)
  const int hq  = h * 4 + w;

  // per-lane swizzled GLOBAL source addresses for direct-to-LDS staging.
  // K tile: 64 rows x 256B (16 units); wave w stages rows 16w..16w+15
  // (4 x 1KB issues of 4 rows). Source unit = slot-unit ^ key(row).
  const int kx = lane >> 4;      // row within issue quad
  const int ku = lane & 15;      // 16B unit within row
  const unsigned short* kgp[4];
#pragma unroll
  for (int i = 0; i < 4; ++i) {
    const int row = 16 * w + 4 * i + kx;                // tile-local kv row
    const int key = (row & 7) ^ ((row >> 3) & 3);
    kgp[i] = Kb + ((size_t)bh * KVL + row) * DH + (ku ^ key) * 8;
  }
  // VT tile: 128 rows(d) x 128B (8 units); wave w stages rows 32w..32w+31
  // (4 x 1KB issues of 8 rows).
  const int vx = lane >> 3;      // row within issue 8-group
  const int vu = lane & 7;       // 16B unit within row
  const unsigned short* vgp[4];
#pragma unroll
  for (int i = 0; i < 4; ++i) {
    const int row = 32 * w + 8 * i + vx;                // d row
    const int key = (row & 7) ^ ((row >> 3) & 3);
    vgp[i] = VTb + ((size_t)bh * DH + row) * KVL + (vu ^ key) * 8;
  }

  auto issue_tile = [&](int buf) {
#pragma unroll
    for (int i = 0; i < 4; ++i)
      load_lds16(kgp[i], &Klds[buf][2048 * w + 512 * i]);
#pragma unroll
    for (int i = 0; i < 4; ++i)
      load_lds16(vgp[i], &Vtlds[buf][2048 * w + 512 * i]);
#pragma unroll
    for (int i = 0; i < 4; ++i) { kgp[i] += 64 * DH; vgp[i] += 64; }
  };

  issue_tile(0);   // start DMA before Q reads

  // fold 1/sqrt(128) * log2(e) into Q (softmax done in exp2 domain)
  const float qscale = 0.08838834764831845f * 1.4426950408889634f;

  // Q B-fragments: lane holds Q[q0+cq][16*ks + 8*hi + j], j=0..7
  bf16x8 qf[8];
  {
    const float* qp = query + (size_t)(b * QL + q0 + cq) * 4096 + hq * DH + 8 * hi;
#pragma unroll
    for (int ks = 0; ks < 8; ++ks) {
      float4 x = *(const float4*)(qp + 16 * ks);
      float4 y = *(const float4*)(qp + 16 * ks + 4);
      uint4 u;
      u.x = pk_bf16(x.x * qscale, x.y * qscale);
      u.y = pk_bf16(x.z * qscale, x.w * qscale);
      u.z = pk_bf16(y.x * qscale, y.y * qscale);
      u.w = pk_bf16(y.z * qscale, y.w * qscale);
      qf[ks] = __builtin_bit_cast(bf16x8, u);
    }
  }

  f32x16 Oacc[4];
#pragma unroll
  for (int dt = 0; dt < 4; ++dt)
#pragma unroll
    for (int i = 0; i < 16; ++i) Oacc[dt][i] = 0.f;
  float Ls = 0.f;

  for (int t = 0; t < n_tiles; ++t) {
    const int buf = t & 1;
    __syncthreads();                           // drains vmcnt: tile t staged
    if (t + 1 < n_tiles) issue_tile(buf ^ 1);  // prefetch overlaps this tile's compute

    // ---- S^T[kv 64][q 32] = K * Q^T  (two 32-kv sub-tiles)
    f32x16 S0, S1;
#pragma unroll
    for (int i = 0; i < 16; ++i) { S0[i] = 0.f; S1[i] = 0.f; }
#pragma unroll
    for (int ks = 0; ks < 8; ++ks) {
      const bf16x8 a0 = __builtin_bit_cast(bf16x8,
          *(const uint4*)&Klds[buf][(cq)      * 128 + 8 * ((2 * ks + hi) ^ xkey)]);
      const bf16x8 a1 = __builtin_bit_cast(bf16x8,
          *(const uint4*)&Klds[buf][(32 + cq) * 128 + 8 * ((2 * ks + hi) ^ xkey)]);
      S0 = __builtin_amdgcn_mfma_f32_32x32x16_bf16(a0, qf[ks], S0, 0, 0, 0);
      S1 = __builtin_amdgcn_mfma_f32_32x32x16_bf16(a1, qf[ks], S1, 0, 0, 0);
    }

    // ---- causal mask: only the last tile is partial; kv_local - q_local > lim
    if (t == n_tiles - 1) {
#pragma unroll
      for (int reg = 0; reg < 16; ++reg) {
        const int rr = (reg & 3) + 8 * (reg >> 2) + 4 * hi;
        if (rr - cq > lim)      S0[reg] = -1e30f;
        if (32 + rr - cq > lim) S1[reg] = -1e30f;
      }
    }

    // ---- softmax + in-register P assembly + PV, per 16-kv step
    auto do_half = [&](const f32x16 &S, int kvt) {
#pragma unroll
      for (int s = 0; s < 2; ++s) {
        // step-local rows: own lanes hold rho {4hi..4hi+3, 8+4hi..8+4hi+3}
        unsigned p01 = pk_trunc(EXP2F(S[8 * s + 0]), EXP2F(S[8 * s + 1]));
        unsigned p23 = pk_trunc(EXP2F(S[8 * s + 2]), EXP2F(S[8 * s + 3]));
        unsigned q01 = pk_trunc(EXP2F(S[8 * s + 4]), EXP2F(S[8 * s + 5]));
        unsigned q23 = pk_trunc(EXP2F(S[8 * s + 6]), EXP2F(S[8 * s + 7]));
        lacc_add(Ls, p01); lacc_add(Ls, p23);
        lacc_add(Ls, q01); lacc_add(Ls, q23);
        // assemble B-frag P^T[rho 16][q 32]: lane needs rho = 8*hi + j
        swap32(p01, q01);   // p01 -> word0 (rho 0,1 | 8,9), q01 -> word2 (rho 4,5 | 12,13)
        swap32(p23, q23);   // p23 -> word1,            q23 -> word3
        uint4 u; u.x = p01; u.y = p23; u.z = q01; u.w = q23;
        const bf16x8 pf = __builtin_bit_cast(bf16x8, u);
        const int ss = 2 * kvt + s;   // kv-step 0..3 within the 64-kv tile
#pragma unroll
        for (int dt = 0; dt < 4; ++dt) {
          const bf16x8 vf = __builtin_bit_cast(bf16x8,
              *(const uint4*)&Vtlds[buf][(32 * dt + cq) * 64 + 8 * ((2 * ss + hi) ^ xkey)]);
          Oacc[dt] = __builtin_amdgcn_mfma_f32_32x32x16_bf16(vf, pf, Oacc[dt], 0, 0, 0);
        }
      }
    };
    do_half(S0, 0);
    do_half(S1, 1);
  }

  // ---- epilogue: cross-half l reduction via shfl_xor (NOT permlane-swap on an
  // aliased pair — see swap32 note), then O = O^T / l
  {
    const float other = __shfl_xor(Ls, 32, 64);
    const float inv = 1.0f / (Ls + other);
    float* op = out + (size_t)(b * QL + q0 + cq) * 4096 + hq * DH + 4 * hi;
#pragma unroll
    for (int dt = 0; dt < 4; ++dt) {
#pragma unroll
      for (int rq = 0; rq < 4; ++rq) {
        float4 o4;
        o4.x = Oacc[dt][4 * rq + 0] * inv;
        o4.y = Oacc[dt][4 * rq + 1] * inv;
        o4.z = Oacc[dt][4 * rq + 2] * inv;
        o4.w = Oacc[dt][4 * rq + 3] * inv;
        *(float4*)(op + 32 * dt + 8 * rq) = o4;
      }
    }
  }
}

extern "C" void kernel_launch(void* const* d_in, const int* in_sizes, int n_in,
                              void* d_out, int out_size, void* d_ws, size_t ws_size,
                              hipStream_t stream) {
  const float* query = (const float*)d_in[0];
  const float* key   = (const float*)d_in[1];
  const float* value = (const float*)d_in[2];
  const float* kc    = (const float*)d_in[3];
  const float* vc    = (const float*)d_in[4];
  const int*   bt    = (const int*)d_in[5];
  float* out = (float*)d_out;

  unsigned short* Kb  = (unsigned short*)d_ws;                 // 16.78 MB
  unsigned short* VTb = Kb + (size_t)32 * KVL * DH;            // + 16.78 MB

  gather_kv_kernel<<<9216, 256, 0, stream>>>(key, kc, value, vc, bt, Kb, VTb);
  attn_kernel<<<512, 256, 0, stream>>>(query, Kb, VTb, out);
}